// Round 11
// baseline (247.296 us; speedup 1.0000x reference)
//
#include <hip/hip_runtime.h>

#define NN 4096
#define CC 32
#define TT 12
#define BB 4
#define BT 48          // BB*TT
#define NC 1536        // BT*CC
#define MAXD 192       // mean degree ~82; P(deg>192) astronomically small
#define FW 512         // features per chunk (8/lane, 16B); chunk slice = 4096*1KB = 4MB
#define NCH 3          // NC / FW
#define STP 36         // k_trans LDS row stride (ushorts)
#define SOP 33         // sOut row stride (floats)

typedef float f32x4 __attribute__((ext_vector_type(4)));
typedef short short8 __attribute__((ext_vector_type(8)));
typedef unsigned short ushort8 __attribute__((ext_vector_type(8)));

__device__ __forceinline__ float bf2f(unsigned short h) {
  return __uint_as_float(((unsigned int)h) << 16);
}
__device__ __forceinline__ unsigned short f2bf(float f) {
  unsigned int u = __float_as_uint(f);
  return (unsigned short)((u + 0x7FFFu + ((u >> 16) & 1u)) >> 16);  // RNE
}
__device__ __forceinline__ float blo(unsigned int w) { return __uint_as_float(w << 16); }
__device__ __forceinline__ float bhi(unsigned int w) { return __uint_as_float(w & 0xFFFF0000u); }

// ---- adjacency (fp32) compaction into edges[].x + degree + d^-1/2 (r3 verbatim)
__global__ __launch_bounds__(256) void k_build(const float* __restrict__ adj,
                                               uint2* __restrict__ edges,
                                               int* __restrict__ deg, float* __restrict__ dis) {
  __shared__ int cnt;
  int m = blockIdx.x;
  if (threadIdx.x == 0) cnt = 0;
  __syncthreads();
  unsigned int* ecol = (unsigned int*)(edges + m * MAXD);
  const uint4* row = (const uint4*)(adj + (size_t)m * NN);
  for (int i = threadIdx.x; i < NN / 4; i += 256) {
    uint4 v = row[i];
    unsigned int ws[4] = {v.x, v.y, v.z, v.w};
    #pragma unroll
    for (int k = 0; k < 4; ++k) {
      if (ws[k] != 0) {
        int p = atomicAdd(&cnt, 1);
        if (p < MAXD) ecol[p * 2] = (unsigned int)(i * 4 + k);
      }
    }
  }
  __syncthreads();
  if (threadIdx.x == 0) {
    int d = cnt < MAXD ? cnt : MAXD;
    deg[m] = d;
    dis[m] = d > 0 ? (float)(1.0 / sqrt((double)d)) : 0.0f;
  }
}

// ---- x[b][c][n][t] (fp32) -> H[n][bt][c] (bf16) via LDS transpose (r3 verbatim).
__global__ __launch_bounds__(256) void k_trans(const float* __restrict__ x,
                                               unsigned short* __restrict__ H) {
  __shared__ unsigned short sT[192 * STP];
  int b = blockIdx.x >> 8;
  int n0 = (blockIdx.x & 255) * 16;
  int c = threadIdx.x >> 3;        // 32 c-groups
  int l8 = threadIdx.x & 7;
  size_t base = ((size_t)(b * CC + c) * NN + n0) * TT;  // 192 contiguous floats per (b,c)
  #pragma unroll
  for (int it = 0; it < 6; ++it) {
    int j0 = it * 32 + l8 * 4;                 // j = nl*12 + t
    float4 f = *(const float4*)(x + base + j0);
    sT[(j0 + 0) * STP + c] = f2bf(f.x);
    sT[(j0 + 1) * STP + c] = f2bf(f.y);
    sT[(j0 + 2) * STP + c] = f2bf(f.z);
    sT[(j0 + 3) * STP + c] = f2bf(f.w);
  }
  __syncthreads();
  #pragma unroll
  for (int k = 0; k < 6; ++k) {
    int p = (threadIdx.x >> 3) + 32 * k;       // 192 (nl,t) runs
    int nl = p / TT, t = p - nl * TT;
    ushort4 v = *(const ushort4*)&sT[p * STP + l8 * 4];
    size_t off = ((size_t)(n0 + nl) * BT + b * TT + t) * CC + l8 * 4;
    *(ushort4*)(H + off) = v;
  }
}

// ---- pure gather (v3 loop, proven 52 us) + in-kernel weight fill (replaces
// the k_wt LAUNCH: row-local work, deterministic values -> the y=0/1/2 blocks
// redundantly write BIT-IDENTICAL bytes, so the write-write race and any K$
// staleness are benign; vmcnt(0) orders each wave's own fill before its
// s_load stream). Gather loop body untouched -> same codegen.
__global__ __launch_bounds__(1024) void k_gather(const unsigned short* __restrict__ S,
                                                 uint2* __restrict__ edges,
                                                 const int* __restrict__ deg,
                                                 const float* __restrict__ dis,
                                                 unsigned short* __restrict__ D) {
  int tid = threadIdx.x;
  int wid = __builtin_amdgcn_readfirstlane(tid >> 6);
  int lane = tid & 63;
  int m = blockIdx.x * 16 + wid;
  int d0 = deg[m];
  int d = (d0 + 15) & ~15;              // padded count (<= MAXD)
  float dm = dis[m];
  uint2* epw = edges + (size_t)m * MAXD;
  // --- fill: weights for [0,d0), {m,0} pads for [d0,d)
  for (int j = lane; j < d; j += 64) {
    if (j < d0) {
      unsigned int c = ((const unsigned int*)epw)[j * 2];   // col from k_build
      epw[j] = make_uint2(c, __float_as_uint(dis[c]));
    } else {
      epw[j] = make_uint2((unsigned int)m, 0u);             // weight 0.0f
    }
  }
  asm volatile("s_waitcnt vmcnt(0)" ::: "memory");          // own fill visible
  const uint2* ep = epw;                                    // wave-uniform stream
  const unsigned short* Sy = S + blockIdx.y * FW;           // uniform base
  int lo2 = lane * 8;                                       // per-lane ushort offset
  float a0 = 0.f, a1 = 0.f, a2 = 0.f, a3 = 0.f;
  float a4 = 0.f, a5 = 0.f, a6 = 0.f, a7 = 0.f;
  for (int e = 0; e < d; e += 8) {
    uint4 hv[8];
    float w[8];
    #pragma unroll
    for (int k = 0; k < 8; ++k) {
      uint2 ew = ep[e + k];             // scalar (batched s_load)
      w[k] = __uint_as_float(ew.y);
      hv[k] = *(const uint4*)(Sy + (int)ew.x * NC + lo2);
    }
    #pragma unroll
    for (int k = 0; k < 8; ++k) {
      float wk = w[k];
      a0 = fmaf(wk, blo(hv[k].x), a0); a1 = fmaf(wk, bhi(hv[k].x), a1);
      a2 = fmaf(wk, blo(hv[k].y), a2); a3 = fmaf(wk, bhi(hv[k].y), a3);
      a4 = fmaf(wk, blo(hv[k].z), a4); a5 = fmaf(wk, bhi(hv[k].z), a5);
      a6 = fmaf(wk, blo(hv[k].w), a6); a7 = fmaf(wk, bhi(hv[k].w), a7);
    }
  }
  int fo = blockIdx.y * FW + lo2;
  ushort8 o;
  o[0] = f2bf(dm * a0); o[1] = f2bf(dm * a1);
  o[2] = f2bf(dm * a2); o[3] = f2bf(dm * a3);
  o[4] = f2bf(dm * a4); o[5] = f2bf(dm * a5);
  o[6] = f2bf(dm * a6); o[7] = f2bf(dm * a7);
  *(ushort8*)(D + (size_t)m * NC + fo) = o;
}

// ---- gather2 + mix fused, chunk-local (r10, 70.4 us; weights already filled
// by k_gather's launch). degp replaced by inline (deg+15)&~15.
#define SEGST(bS, tS, lS, rr) {                                              \
    const int nq = (lS) / 4;                                                 \
    int o = (rr) / (16 * nq);                                                \
    int rem = (rr) - o * (16 * nq);                                          \
    int nl = rem / nq, q = rem - nl * nq;                                    \
    int rw = (bS) * 12 + (tS) + q * 4 - yy * 16;                             \
    float4 v = make_float4(sOut[nl][rw + 0][o], sOut[nl][rw + 1][o],         \
                           sOut[nl][rw + 2][o], sOut[nl][rw + 3][o]);        \
    size_t gb = (((size_t)((bS) * CC + o) * NN) + n0 + nl) * TT + (tS) + q * 4; \
    *(float4*)(out + gb) = v; }

__global__ __launch_bounds__(1024) void k_gmix(
    const unsigned short* __restrict__ G1,
    const unsigned short* __restrict__ H,
    const uint2* __restrict__ edges,
    const int* __restrict__ deg,
    const float* __restrict__ dis,
    const float* __restrict__ W,
    const float* __restrict__ bias,
    float* __restrict__ out) {
  __shared__ __align__(16) unsigned short sG2[16][16][CC];  // 16 KB, wave-private
  __shared__ __align__(16) float sOut[16][17][SOP];         // 35.9 KB (node-dim pad)
  int tid = threadIdx.x;
  int wid = __builtin_amdgcn_readfirstlane(tid >> 6);
  int lane = tid & 63;
  int n0 = blockIdx.x * 16;
  int m = n0 + wid;
  int yy = blockIdx.y;
  int d = (deg[m] + 15) & ~15;
  float dm = dis[m];
  const uint2* ep = edges + (size_t)m * MAXD;
  const unsigned short* Sy = G1 + yy * FW;
  int lo2 = lane * 8;
  float a0 = 0.f, a1 = 0.f, a2 = 0.f, a3 = 0.f;
  float a4 = 0.f, a5 = 0.f, a6 = 0.f, a7 = 0.f;
  for (int e = 0; e < d; e += 8) {
    uint4 hv[8];
    float w[8];
    #pragma unroll
    for (int k = 0; k < 8; ++k) {
      uint2 ew = ep[e + k];             // scalar (batched s_load)
      w[k] = __uint_as_float(ew.y);
      hv[k] = *(const uint4*)(Sy + (int)ew.x * NC + lo2);
    }
    #pragma unroll
    for (int k = 0; k < 8; ++k) {
      float wk = w[k];
      a0 = fmaf(wk, blo(hv[k].x), a0); a1 = fmaf(wk, bhi(hv[k].x), a1);
      a2 = fmaf(wk, blo(hv[k].y), a2); a3 = fmaf(wk, bhi(hv[k].y), a3);
      a4 = fmaf(wk, blo(hv[k].z), a4); a5 = fmaf(wk, bhi(hv[k].z), a5);
      a6 = fmaf(wk, blo(hv[k].w), a6); a7 = fmaf(wk, bhi(hv[k].w), a7);
    }
  }
  // G2 tile, bf16 -- bit-identical to the v3-stored G2 values
  ushort8 go;
  go[0] = f2bf(dm * a0); go[1] = f2bf(dm * a1);
  go[2] = f2bf(dm * a2); go[3] = f2bf(dm * a3);
  go[4] = f2bf(dm * a4); go[5] = f2bf(dm * a5);
  go[6] = f2bf(dm * a6); go[7] = f2bf(dm * a7);
  *(ushort8*)&sG2[wid][lane >> 2][(lane & 3) * 8] = go;   // wave-private permute
  // ---- mix (identical math/order to proven k_mix)
  int lm = lane & 15, quad = lane >> 4;
  size_t abase = ((size_t)m * BT + yy * 16 + lm) * CC + quad * 8;
  short8 af0 = *(const short8*)(H + abase);
  short8 af1 = *(const short8*)(G1 + abase);
  short8 af2 = *(const short8*)&sG2[wid][lm][quad * 8];
  #pragma unroll
  for (int h = 0; h < 2; ++h) {
    float bs = bias[h * 16 + lm];
    f32x4 acc = {bs, bs, bs, bs};
    #pragma unroll
    for (int g = 0; g < 3; ++g) {
      short8 vh, vl;
      #pragma unroll
      for (int j = 0; j < 8; ++j) {
        int r = quad * 8 + j, c = h * 16 + lm;
        float w0 = W[(0 * CC + r) * CC + c];
        float w1 = W[(1 * CC + r) * CC + c];
        float w2 = W[(2 * CC + r) * CC + c];
        float w = (g == 0) ? (w0 + w1 + w2)
                 : (g == 1) ? (-w1 - 4.f * w2)
                            : (2.f * w2);
        unsigned short hi = f2bf(w);
        vh[j] = (short)hi;
        vl[j] = (short)f2bf(w - bf2f(hi));
      }
      short8 af = (g == 0) ? af0 : (g == 1) ? af1 : af2;
      acc = __builtin_amdgcn_mfma_f32_16x16x32_bf16(af, vh, acc, 0, 0, 0);
      acc = __builtin_amdgcn_mfma_f32_16x16x32_bf16(af, vl, acc, 0, 0, 0);
    }
    int o = h * 16 + lm;
    #pragma unroll
    for (int reg = 0; reg < 4; ++reg)
      sOut[wid][quad * 4 + reg][o] = acc[reg];
  }
  __syncthreads();
  // ---- per-segment coalesced stores: 2048 float4s, 2 per thread.
  // y0:(b0,t0,12)+(b1,t0,4)  y1:(b1,t4,8)+(b2,t0,8)  y2:(b2,t8,4)+(b3,t0,12)
  if (yy == 0) {
    #pragma unroll
    for (int j = 0; j < 2; ++j) {
      int idx = j * 1024 + tid;
      if (idx < 1536) SEGST(0, 0, 12, idx) else SEGST(1, 0, 4, idx - 1536)
    }
  } else if (yy == 1) {
    #pragma unroll
    for (int j = 0; j < 2; ++j) {
      int idx = j * 1024 + tid;
      if (idx < 1024) SEGST(1, 4, 8, idx) else SEGST(2, 0, 8, idx - 1024)
    }
  } else {
    #pragma unroll
    for (int j = 0; j < 2; ++j) {
      int idx = j * 1024 + tid;
      if (idx < 512) SEGST(2, 8, 4, idx) else SEGST(3, 0, 12, idx - 512)
    }
  }
}

extern "C" void kernel_launch(void* const* d_in, const int* in_sizes, int n_in,
                              void* d_out, int out_size, void* d_ws, size_t ws_size,
                              hipStream_t stream) {
  const float* x    = (const float*)d_in[0];
  const float* adj  = (const float*)d_in[1];
  const float* wgt  = (const float*)d_in[2];
  const float* bias = (const float*)d_in[3];
  char* ws = (char*)d_ws;
  float* dis  = (float*)ws;                                 // 16 KB
  int*   deg  = (int*)(ws + 16384);                         // 16 KB
  uint2* edges = (uint2*)(ws + 32768);                      // 6.29 MB
  char* p = ws + 32768 + (size_t)NN * MAXD * 8;
  unsigned short* H  = (unsigned short*)p;                  // 12.58 MB
  unsigned short* G1 = (unsigned short*)(p + (size_t)NN * NC * 2);

  k_build<<<NN, 256, 0, stream>>>(adj, edges, deg, dis);
  k_trans<<<1024, 256, 0, stream>>>(x, H);
  k_gather<<<dim3(NN / 16, NCH), 1024, 0, stream>>>(H, edges, deg, dis, G1);
  k_gmix<<<dim3(NN / 16, NCH), 1024, 0, stream>>>(G1, H, edges, deg, dis,
                                                  wgt, bias, (float*)d_out);
}

// Round 12
// 234.956 us; speedup vs baseline: 1.0525x; 1.0525x over previous
//
#include <hip/hip_runtime.h>

#define NN 4096
#define CC 32
#define TT 12
#define BB 4
#define BT 48          // BB*TT
#define NC 1536        // BT*CC
#define MAXD 192       // mean degree ~82; P(deg>192) astronomically small
#define FW 512         // features per chunk (8/lane, 16B); chunk slice = 4096*1KB = 4MB
#define NCH 3          // NC / FW
#define STP 36         // k_trans LDS row stride (ushorts)
#define SOP 33         // sOut row stride (floats)

typedef float f32x4 __attribute__((ext_vector_type(4)));
typedef short short8 __attribute__((ext_vector_type(8)));
typedef unsigned short ushort8 __attribute__((ext_vector_type(8)));

__device__ __forceinline__ float bf2f(unsigned short h) {
  return __uint_as_float(((unsigned int)h) << 16);
}
__device__ __forceinline__ unsigned short f2bf(float f) {
  unsigned int u = __float_as_uint(f);
  return (unsigned short)((u + 0x7FFFu + ((u >> 16) & 1u)) >> 16);  // RNE
}
__device__ __forceinline__ float blo(unsigned int w) { return __uint_as_float(w << 16); }
__device__ __forceinline__ float bhi(unsigned int w) { return __uint_as_float(w & 0xFFFF0000u); }

// ---- adjacency (fp32) compaction into col-only edge list + degree + d^-1/2.
// r11 lesson: k_wt's WORK is free, its LAUNCH isn't; and relocating the fill
// into the gather as an RMW prefix regressed. So: no weights stored at all --
// gathers load dis[col] lazily (wave-uniform s_load, hidden under payload
// latency). Pads (col=m, <=15) written here by thread 0; weight forced to 0
// in-loop by a uniform select. Bit-identical weights and FMA order.
__global__ __launch_bounds__(256) void k_build(const float* __restrict__ adj,
                                               unsigned int* __restrict__ ecols,
                                               int* __restrict__ deg, float* __restrict__ dis) {
  __shared__ int cnt;
  int m = blockIdx.x;
  if (threadIdx.x == 0) cnt = 0;
  __syncthreads();
  unsigned int* ecol = ecols + (size_t)m * MAXD;
  const uint4* row = (const uint4*)(adj + (size_t)m * NN);
  for (int i = threadIdx.x; i < NN / 4; i += 256) {
    uint4 v = row[i];
    unsigned int ws[4] = {v.x, v.y, v.z, v.w};
    #pragma unroll
    for (int k = 0; k < 4; ++k) {
      if (ws[k] != 0) {
        int p = atomicAdd(&cnt, 1);
        if (p < MAXD) ecol[p] = (unsigned int)(i * 4 + k);
      }
    }
  }
  __syncthreads();
  if (threadIdx.x == 0) {
    int d = cnt < MAXD ? cnt : MAXD;
    deg[m] = d;
    dis[m] = d > 0 ? (float)(1.0 / sqrt((double)d)) : 0.0f;
    int dp = (d + 15) & ~15;
    for (int j = d; j < dp; ++j) ecol[j] = (unsigned int)m;  // pad cols
  }
}

// ---- x[b][c][n][t] (fp32) -> H[n][bt][c] (bf16) via LDS transpose (r3 verbatim).
__global__ __launch_bounds__(256) void k_trans(const float* __restrict__ x,
                                               unsigned short* __restrict__ H) {
  __shared__ unsigned short sT[192 * STP];
  int b = blockIdx.x >> 8;
  int n0 = (blockIdx.x & 255) * 16;
  int c = threadIdx.x >> 3;        // 32 c-groups
  int l8 = threadIdx.x & 7;
  size_t base = ((size_t)(b * CC + c) * NN + n0) * TT;  // 192 contiguous floats per (b,c)
  #pragma unroll
  for (int it = 0; it < 6; ++it) {
    int j0 = it * 32 + l8 * 4;                 // j = nl*12 + t
    float4 f = *(const float4*)(x + base + j0);
    sT[(j0 + 0) * STP + c] = f2bf(f.x);
    sT[(j0 + 1) * STP + c] = f2bf(f.y);
    sT[(j0 + 2) * STP + c] = f2bf(f.z);
    sT[(j0 + 3) * STP + c] = f2bf(f.w);
  }
  __syncthreads();
  #pragma unroll
  for (int k = 0; k < 6; ++k) {
    int p = (threadIdx.x >> 3) + 32 * k;       // 192 (nl,t) runs
    int nl = p / TT, t = p - nl * TT;
    ushort4 v = *(const ushort4*)&sT[p * STP + l8 * 4];
    size_t off = ((size_t)(n0 + nl) * BT + b * TT + t) * CC + l8 * 4;
    *(ushort4*)(H + off) = v;
  }
}

// ---- pure gather (v3 loop): D[m,q] = dis[m]*sum_e dis[col]*S[col,q]
// Edge stream = col-only uint (half the scalar bytes); weight = lazy s_load
// dis[col] + uniform select for pads. Payload address chain unchanged.
__global__ __launch_bounds__(1024) void k_gather(const unsigned short* __restrict__ S,
                                                 const unsigned int* __restrict__ ecols,
                                                 const int* __restrict__ deg,
                                                 const float* __restrict__ dis,
                                                 unsigned short* __restrict__ D) {
  int tid = threadIdx.x;
  int wid = __builtin_amdgcn_readfirstlane(tid >> 6);
  int lane = tid & 63;
  int m = blockIdx.x * 16 + wid;
  int d0 = deg[m];
  int d = (d0 + 15) & ~15;              // padded count (pads exist, col=m)
  float dm = dis[m];
  const unsigned int* ep = ecols + (size_t)m * MAXD;  // wave-uniform stream
  const unsigned short* Sy = S + blockIdx.y * FW;     // uniform base
  int lo2 = lane * 8;                                 // per-lane ushort offset (16B)
  float a0 = 0.f, a1 = 0.f, a2 = 0.f, a3 = 0.f;
  float a4 = 0.f, a5 = 0.f, a6 = 0.f, a7 = 0.f;
  for (int e = 0; e < d; e += 8) {
    uint4 hv[8];
    float w[8];
    #pragma unroll
    for (int k = 0; k < 8; ++k) {
      int c = (int)ep[e + k];           // scalar (batched s_load)
      float wc = dis[c];                // scalar, hidden under payload latency
      w[k] = (e + k < d0) ? wc : 0.0f;  // uniform select (pads -> 0)
      hv[k] = *(const uint4*)(Sy + c * NC + lo2);
    }
    #pragma unroll
    for (int k = 0; k < 8; ++k) {
      float wk = w[k];
      a0 = fmaf(wk, blo(hv[k].x), a0); a1 = fmaf(wk, bhi(hv[k].x), a1);
      a2 = fmaf(wk, blo(hv[k].y), a2); a3 = fmaf(wk, bhi(hv[k].y), a3);
      a4 = fmaf(wk, blo(hv[k].z), a4); a5 = fmaf(wk, bhi(hv[k].z), a5);
      a6 = fmaf(wk, blo(hv[k].w), a6); a7 = fmaf(wk, bhi(hv[k].w), a7);
    }
  }
  int fo = blockIdx.y * FW + lo2;
  ushort8 o;
  o[0] = f2bf(dm * a0); o[1] = f2bf(dm * a1);
  o[2] = f2bf(dm * a2); o[3] = f2bf(dm * a3);
  o[4] = f2bf(dm * a4); o[5] = f2bf(dm * a5);
  o[6] = f2bf(dm * a6); o[7] = f2bf(dm * a7);
  *(ushort8*)(D + (size_t)m * NC + fo) = o;
}

// ---- gather2 + mix fused, chunk-local (r10 body; edge format updated).
#define SEGST(bS, tS, lS, rr) {                                              \
    const int nq = (lS) / 4;                                                 \
    int o = (rr) / (16 * nq);                                                \
    int rem = (rr) - o * (16 * nq);                                          \
    int nl = rem / nq, q = rem - nl * nq;                                    \
    int rw = (bS) * 12 + (tS) + q * 4 - yy * 16;                             \
    float4 v = make_float4(sOut[nl][rw + 0][o], sOut[nl][rw + 1][o],         \
                           sOut[nl][rw + 2][o], sOut[nl][rw + 3][o]);        \
    size_t gb = (((size_t)((bS) * CC + o) * NN) + n0 + nl) * TT + (tS) + q * 4; \
    *(float4*)(out + gb) = v; }

__global__ __launch_bounds__(1024) void k_gmix(
    const unsigned short* __restrict__ G1,
    const unsigned short* __restrict__ H,
    const unsigned int* __restrict__ ecols,
    const int* __restrict__ deg,
    const float* __restrict__ dis,
    const float* __restrict__ W,
    const float* __restrict__ bias,
    float* __restrict__ out) {
  __shared__ __align__(16) unsigned short sG2[16][16][CC];  // 16 KB, wave-private
  __shared__ __align__(16) float sOut[16][17][SOP];         // 35.9 KB (node-dim pad)
  int tid = threadIdx.x;
  int wid = __builtin_amdgcn_readfirstlane(tid >> 6);
  int lane = tid & 63;
  int n0 = blockIdx.x * 16;
  int m = n0 + wid;
  int yy = blockIdx.y;
  int d0 = deg[m];
  int d = (d0 + 15) & ~15;
  float dm = dis[m];
  const unsigned int* ep = ecols + (size_t)m * MAXD;
  const unsigned short* Sy = G1 + yy * FW;
  int lo2 = lane * 8;
  float a0 = 0.f, a1 = 0.f, a2 = 0.f, a3 = 0.f;
  float a4 = 0.f, a5 = 0.f, a6 = 0.f, a7 = 0.f;
  for (int e = 0; e < d; e += 8) {
    uint4 hv[8];
    float w[8];
    #pragma unroll
    for (int k = 0; k < 8; ++k) {
      int c = (int)ep[e + k];           // scalar (batched s_load)
      float wc = dis[c];
      w[k] = (e + k < d0) ? wc : 0.0f;
      hv[k] = *(const uint4*)(Sy + c * NC + lo2);
    }
    #pragma unroll
    for (int k = 0; k < 8; ++k) {
      float wk = w[k];
      a0 = fmaf(wk, blo(hv[k].x), a0); a1 = fmaf(wk, bhi(hv[k].x), a1);
      a2 = fmaf(wk, blo(hv[k].y), a2); a3 = fmaf(wk, bhi(hv[k].y), a3);
      a4 = fmaf(wk, blo(hv[k].z), a4); a5 = fmaf(wk, bhi(hv[k].z), a5);
      a6 = fmaf(wk, blo(hv[k].w), a6); a7 = fmaf(wk, bhi(hv[k].w), a7);
    }
  }
  // G2 tile, bf16 -- bit-identical to the v3-stored G2 values
  ushort8 go;
  go[0] = f2bf(dm * a0); go[1] = f2bf(dm * a1);
  go[2] = f2bf(dm * a2); go[3] = f2bf(dm * a3);
  go[4] = f2bf(dm * a4); go[5] = f2bf(dm * a5);
  go[6] = f2bf(dm * a6); go[7] = f2bf(dm * a7);
  *(ushort8*)&sG2[wid][lane >> 2][(lane & 3) * 8] = go;   // wave-private permute
  // ---- mix (identical math/order to proven k_mix)
  int lm = lane & 15, quad = lane >> 4;
  size_t abase = ((size_t)m * BT + yy * 16 + lm) * CC + quad * 8;
  short8 af0 = *(const short8*)(H + abase);
  short8 af1 = *(const short8*)(G1 + abase);
  short8 af2 = *(const short8*)&sG2[wid][lm][quad * 8];
  #pragma unroll
  for (int h = 0; h < 2; ++h) {
    float bs = bias[h * 16 + lm];
    f32x4 acc = {bs, bs, bs, bs};
    #pragma unroll
    for (int g = 0; g < 3; ++g) {
      short8 vh, vl;
      #pragma unroll
      for (int j = 0; j < 8; ++j) {
        int r = quad * 8 + j, c = h * 16 + lm;
        float w0 = W[(0 * CC + r) * CC + c];
        float w1 = W[(1 * CC + r) * CC + c];
        float w2 = W[(2 * CC + r) * CC + c];
        float w = (g == 0) ? (w0 + w1 + w2)
                 : (g == 1) ? (-w1 - 4.f * w2)
                            : (2.f * w2);
        unsigned short hi = f2bf(w);
        vh[j] = (short)hi;
        vl[j] = (short)f2bf(w - bf2f(hi));
      }
      short8 af = (g == 0) ? af0 : (g == 1) ? af1 : af2;
      acc = __builtin_amdgcn_mfma_f32_16x16x32_bf16(af, vh, acc, 0, 0, 0);
      acc = __builtin_amdgcn_mfma_f32_16x16x32_bf16(af, vl, acc, 0, 0, 0);
    }
    int o = h * 16 + lm;
    #pragma unroll
    for (int reg = 0; reg < 4; ++reg)
      sOut[wid][quad * 4 + reg][o] = acc[reg];
  }
  __syncthreads();
  // ---- per-segment coalesced stores: 2048 float4s, 2 per thread.
  // y0:(b0,t0,12)+(b1,t0,4)  y1:(b1,t4,8)+(b2,t0,8)  y2:(b2,t8,4)+(b3,t0,12)
  if (yy == 0) {
    #pragma unroll
    for (int j = 0; j < 2; ++j) {
      int idx = j * 1024 + tid;
      if (idx < 1536) SEGST(0, 0, 12, idx) else SEGST(1, 0, 4, idx - 1536)
    }
  } else if (yy == 1) {
    #pragma unroll
    for (int j = 0; j < 2; ++j) {
      int idx = j * 1024 + tid;
      if (idx < 1024) SEGST(1, 4, 8, idx) else SEGST(2, 0, 8, idx - 1024)
    }
  } else {
    #pragma unroll
    for (int j = 0; j < 2; ++j) {
      int idx = j * 1024 + tid;
      if (idx < 512) SEGST(2, 8, 4, idx) else SEGST(3, 0, 12, idx - 512)
    }
  }
}

extern "C" void kernel_launch(void* const* d_in, const int* in_sizes, int n_in,
                              void* d_out, int out_size, void* d_ws, size_t ws_size,
                              hipStream_t stream) {
  const float* x    = (const float*)d_in[0];
  const float* adj  = (const float*)d_in[1];
  const float* wgt  = (const float*)d_in[2];
  const float* bias = (const float*)d_in[3];
  char* ws = (char*)d_ws;
  float* dis  = (float*)ws;                                 // 16 KB
  int*   deg  = (int*)(ws + 16384);                         // 16 KB
  unsigned int* ecols = (unsigned int*)(ws + 32768);        // 3.15 MB
  char* p = ws + 32768 + (size_t)NN * MAXD * 4;
  unsigned short* H  = (unsigned short*)p;                  // 12.58 MB
  unsigned short* G1 = (unsigned short*)(p + (size_t)NN * NC * 2);

  k_build<<<NN, 256, 0, stream>>>(adj, ecols, deg, dis);
  k_trans<<<1024, 256, 0, stream>>>(x, H);
  k_gather<<<dim3(NN / 16, NCH), 1024, 0, stream>>>(H, ecols, deg, dis, G1);
  k_gmix<<<dim3(NN / 16, NCH), 1024, 0, stream>>>(G1, H, ecols, deg, dis,
                                                  wgt, bias, (float*)d_out);
}